// Round 4
// baseline (240.092 us; speedup 1.0000x reference)
//
#include <hip/hip_runtime.h>
#include <cstdint>
#include <cstddef>

#define DIM 128
#define HEADS 4

typedef __attribute__((ext_vector_type(8))) short bf16x8;
typedef __attribute__((ext_vector_type(4))) float f32x4;

__device__ __forceinline__ ushort f2bf(float x) {
    union { float f; uint32_t u; } v; v.f = x;
    uint32_t r = v.u + 0x7FFFu + ((v.u >> 16) & 1u);   // RNE
    return (ushort)(r >> 16);
}
__device__ __forceinline__ float bf2f(ushort h) {
    union { uint32_t u; float f; } v; v.u = ((uint32_t)h) << 16; return v.f;
}

// ---------------------------------------------------------------------------
// wtrans: W[k][col] f32 -> Wt[w][col][k] bf16 hi/lo (transposed for B-frags)
// ---------------------------------------------------------------------------
__global__ __launch_bounds__(256)
void wtrans(const float* __restrict__ qW, const float* __restrict__ kW,
            const float* __restrict__ vW,
            ushort* __restrict__ WtHi, ushort* __restrict__ WtLo)
{
    int t = blockIdx.x * 256 + threadIdx.x;      // 3*128*128 = 49152
    int w = t >> 14;
    int rem = t & 16383;
    int col = rem >> 7;
    int k = rem & 127;
    const float* W = (w == 0) ? qW : (w == 1) ? kW : vW;
    float x = W[k * DIM + col];
    ushort hi = f2bf(x);
    ushort lo = f2bf(x - bf2f(hi));
    WtHi[t] = hi;                                // [w][col][k]
    WtLo[t] = lo;
}

// ---------------------------------------------------------------------------
// qkv_mfma: fused Q,K,V = emb @ {qW,kW,vW} via 3-term hi/lo bf16 MFMA.
// 512 threads = 8 waves (4 row-groups x 2 col-halves), 128 rows/block.
// Full K=128 A tile staged hi/lo in LDS ONCE (64KB, single barrier),
// reused for all 3 weight matrices. B frags read direct from global
// (Wt is 196KB total, L2-resident). XOR-swizzled LDS (G4).
// MFMA term order per accumulator identical to R2 (bit-exact outputs).
// ---------------------------------------------------------------------------
__global__ __launch_bounds__(512)
void qkv_mfma(const float* __restrict__ emb,
              const ushort* __restrict__ WtHi, const ushort* __restrict__ WtLo,
              ushort* __restrict__ Qb, ushort* __restrict__ Kb,
              ushort* __restrict__ Vb, int N)
{
    __shared__ ushort Ahi[128 * 128];   // [row][k], 32KB, swizzled
    __shared__ ushort Alo[128 * 128];   // 32KB

    const int tid = threadIdx.x;
    const int wv = tid >> 6;
    const int ln = tid & 63;
    const int l15 = ln & 15;
    const int l4 = ln >> 4;
    const int wm = wv & 3;              // row group (32 rows)
    const int wn = wv >> 2;             // col half (64 cols)
    const int m0 = blockIdx.x * 128;

    // ---- stage A: 128 rows x 128 k, f32 -> bf16 hi/lo, once ----
#pragma unroll
    for (int p = 0; p < 8; p++) {
        int idx = tid + p * 512;            // 0..4095
        int row = idx >> 5;                 // 0..127
        int k4 = (idx & 31) << 2;           // 0..124
        float4 a = make_float4(0.f, 0.f, 0.f, 0.f);
        if (m0 + row < N)
            a = *(const float4*)(emb + (size_t)(m0 + row) * DIM + k4);
        ushort4 h, l;
        h.x = f2bf(a.x); l.x = f2bf(a.x - bf2f(h.x));
        h.y = f2bf(a.y); l.y = f2bf(a.y - bf2f(h.y));
        h.z = f2bf(a.z); l.z = f2bf(a.z - bf2f(h.z));
        h.w = f2bf(a.w); l.w = f2bf(a.w - bf2f(h.w));
        int boff = row * 256 + ((k4 * 2) ^ ((row & 7) << 4));
        *(ushort4*)((char*)Ahi + boff) = h;
        *(ushort4*)((char*)Alo + boff) = l;
    }
    __syncthreads();

    for (int wsel = 0; wsel < 3; wsel++) {
        const ushort* __restrict__ Wh = WtHi + wsel * DIM * DIM;
        const ushort* __restrict__ Wl = WtLo + wsel * DIM * DIM;
        ushort* __restrict__ Out = (wsel == 0) ? Qb : (wsel == 1) ? Kb : Vb;

        f32x4 acc[2][4] = {};

#pragma unroll
        for (int s = 0; s < 4; s++) {       // k-slice: k = s*32 + l4*8 .. +8
            bf16x8 ah[2], al[2];
#pragma unroll
            for (int fr = 0; fr < 2; fr++) {
                int row = wm * 32 + fr * 16 + l15;
                int boff = row * 256 + ((s * 64 + l4 * 16) ^ ((row & 7) << 4));
                ah[fr] = *(bf16x8*)((char*)Ahi + boff);
                al[fr] = *(bf16x8*)((char*)Alo + boff);
            }
#pragma unroll
            for (int n = 0; n < 4; n++) {
                int col = wn * 64 + n * 16 + l15;
                size_t goff = (size_t)col * DIM + s * 32 + l4 * 8;
                bf16x8 bh = *(const bf16x8*)(Wh + goff);
                bf16x8 bl = *(const bf16x8*)(Wl + goff);
#pragma unroll
                for (int fr = 0; fr < 2; fr++) {
                    acc[fr][n] = __builtin_amdgcn_mfma_f32_16x16x32_bf16(ah[fr], bh, acc[fr][n], 0, 0, 0);
                    acc[fr][n] = __builtin_amdgcn_mfma_f32_16x16x32_bf16(al[fr], bh, acc[fr][n], 0, 0, 0);
                    acc[fr][n] = __builtin_amdgcn_mfma_f32_16x16x32_bf16(ah[fr], bl, acc[fr][n], 0, 0, 0);
                }
            }
        }

        // ---- epilogue: C/D layout col=lane&15, row=(lane>>4)*4+j ----
#pragma unroll
        for (int fr = 0; fr < 2; fr++) {
            int rbase = m0 + wm * 32 + fr * 16 + l4 * 4;
#pragma unroll
            for (int n = 0; n < 4; n++) {
                int col = wn * 64 + n * 16 + l15;
#pragma unroll
                for (int j = 0; j < 4; j++) {
                    int r = rbase + j;
                    if (r < N) Out[(size_t)r * DIM + col] = f2bf(acc[fr][n][j]);
                }
            }
        }
        // no barrier needed: LDS is read-only after the single stage
    }
}

// ---------------------------------------------------------------------------
// CSR build: degree count -> exclusive scan -> permutation fill (+ colsCSR).
// ---------------------------------------------------------------------------
__global__ __launch_bounds__(256)
void count_degree(const int* __restrict__ rows, int* __restrict__ degree, int E)
{
    int e = blockIdx.x * 256 + threadIdx.x;
    if (e < E) atomicAdd(&degree[rows[e]], 1);
}

__global__ __launch_bounds__(256)
void scanA(const int* __restrict__ degree, int* __restrict__ rowPtr,
           int* __restrict__ blockSums, int N)
{
    __shared__ int s[256];
    const int tid = threadIdx.x;
    const int base = blockIdx.x * 1024 + tid * 4;
    int d[4];
    int tsum = 0;
#pragma unroll
    for (int i = 0; i < 4; i++) {
        d[i] = (base + i < N) ? degree[base + i] : 0;
        tsum += d[i];
    }
    s[tid] = tsum;
    __syncthreads();
    for (int off = 1; off < 256; off <<= 1) {
        int v = (tid >= off) ? s[tid - off] : 0;
        __syncthreads();
        s[tid] += v;
        __syncthreads();
    }
    if (tid == 255) blockSums[blockIdx.x] = s[255];
    int running = s[tid] - tsum;
#pragma unroll
    for (int i = 0; i < 4; i++) {
        if (base + i < N) rowPtr[base + i] = running;
        running += d[i];
    }
}

__global__ __launch_bounds__(256)
void scanB(int* __restrict__ blockSums, int nb)
{
    __shared__ int s[256];
    const int tid = threadIdx.x;
    int v = (tid < nb) ? blockSums[tid] : 0;
    s[tid] = v;
    __syncthreads();
    for (int off = 1; off < 256; off <<= 1) {
        int u = (tid >= off) ? s[tid - off] : 0;
        __syncthreads();
        s[tid] += u;
        __syncthreads();
    }
    if (tid < nb) blockSums[tid] = s[tid] - v;
}

__global__ __launch_bounds__(256)
void scanC(int* __restrict__ rowPtr, const int* __restrict__ blockSums,
           int* __restrict__ cursor, int N, int E)
{
    const int tid = threadIdx.x;
    const int base = blockIdx.x * 1024 + tid * 4;
    const int off = blockSums[blockIdx.x];
#pragma unroll
    for (int i = 0; i < 4; i++) {
        int idx = base + i;
        if (idx < N) {
            int v = rowPtr[idx] + off;
            rowPtr[idx] = v;
            cursor[idx] = v;
        }
    }
    if (blockIdx.x == 0 && tid == 0) rowPtr[N] = E;
}

__global__ __launch_bounds__(256)
void fill_perm(const int* __restrict__ rows, const int* __restrict__ cols,
               int* __restrict__ cursor, int* __restrict__ perm,
               int* __restrict__ colsCSR, int E)
{
    int e = blockIdx.x * 256 + threadIdx.x;
    if (e >= E) return;
    int pos = atomicAdd(&cursor[rows[e]], 1);
    perm[pos] = e;
    colsCSR[pos] = cols[e];
}

// ---------------------------------------------------------------------------
// csr_fused: per node (32 lanes), unroll-2 pass over its edges:
// logits (8-lane shfl reduce per head) -> exp -> norm + unnormalized ex*V acc.
// Accumulation order identical to the serial loop (bit-exact).
// ---------------------------------------------------------------------------
__global__ __launch_bounds__(256)
void csr_fused(const ushort* __restrict__ Qb, const ushort* __restrict__ Kb,
               const ushort* __restrict__ Vb,
               const int* __restrict__ rowPtr, const int* __restrict__ perm,
               const int* __restrict__ colsCSR,
               float* __restrict__ attBuf, float* __restrict__ invNorm,
               float* __restrict__ out, int N)
{
    int t = blockIdx.x * 256 + threadIdx.x;
    int node = t >> 5;
    int lane = t & 31;
    if (node >= N) return;

    const int start = rowPtr[node];
    const int end   = rowPtr[node + 1];
    const int h = lane >> 3;

    ushort4 qu = *(const ushort4*)(Qb + (size_t)node * DIM + lane * 4);
    float4 q = make_float4(bf2f(qu.x), bf2f(qu.y), bf2f(qu.z), bf2f(qu.w));

    float norm = 0.f;
    float4 acc = make_float4(0.f, 0.f, 0.f, 0.f);

    int p = start;
    for (; p + 2 <= end; p += 2) {
        int c0 = colsCSR[p];
        int c1 = colsCSR[p + 1];
        int e0 = perm[p];
        int e1 = perm[p + 1];
        ushort4 k0 = *(const ushort4*)(Kb + (size_t)c0 * DIM + lane * 4);
        ushort4 v0 = *(const ushort4*)(Vb + (size_t)c0 * DIM + lane * 4);
        ushort4 k1 = *(const ushort4*)(Kb + (size_t)c1 * DIM + lane * 4);
        ushort4 v1 = *(const ushort4*)(Vb + (size_t)c1 * DIM + lane * 4);
        float d0 = bf2f(k0.x) * q.x + bf2f(k0.y) * q.y
                 + bf2f(k0.z) * q.z + bf2f(k0.w) * q.w;
        float d1 = bf2f(k1.x) * q.x + bf2f(k1.y) * q.y
                 + bf2f(k1.z) * q.z + bf2f(k1.w) * q.w;
        d0 += __shfl_xor(d0, 1, 64);
        d1 += __shfl_xor(d1, 1, 64);
        d0 += __shfl_xor(d0, 2, 64);
        d1 += __shfl_xor(d1, 2, 64);
        d0 += __shfl_xor(d0, 4, 64);
        d1 += __shfl_xor(d1, 4, 64);
        d0 = fminf(fmaxf(d0, -10.f), 10.f);
        d1 = fminf(fmaxf(d1, -10.f), 10.f);
        float ex0 = __expf(d0);
        float ex1 = __expf(d1);
        if ((lane & 7) == 0) {
            attBuf[(size_t)e0 * HEADS + h] = ex0;
            attBuf[(size_t)e1 * HEADS + h] = ex1;
        }
        norm += ex0;
        norm += ex1;
        acc.x += ex0 * bf2f(v0.x);
        acc.y += ex0 * bf2f(v0.y);
        acc.z += ex0 * bf2f(v0.z);
        acc.w += ex0 * bf2f(v0.w);
        acc.x += ex1 * bf2f(v1.x);
        acc.y += ex1 * bf2f(v1.y);
        acc.z += ex1 * bf2f(v1.z);
        acc.w += ex1 * bf2f(v1.w);
    }
    if (p < end) {
        int c = colsCSR[p];
        int e = perm[p];
        ushort4 ku = *(const ushort4*)(Kb + (size_t)c * DIM + lane * 4);
        ushort4 vu = *(const ushort4*)(Vb + (size_t)c * DIM + lane * 4);
        float d = bf2f(ku.x) * q.x + bf2f(ku.y) * q.y
                + bf2f(ku.z) * q.z + bf2f(ku.w) * q.w;
        d += __shfl_xor(d, 1, 64);
        d += __shfl_xor(d, 2, 64);
        d += __shfl_xor(d, 4, 64);
        d = fminf(fmaxf(d, -10.f), 10.f);
        float ex = __expf(d);
        if ((lane & 7) == 0) attBuf[(size_t)e * HEADS + h] = ex;
        norm += ex;
        acc.x += ex * bf2f(vu.x);
        acc.y += ex * bf2f(vu.y);
        acc.z += ex * bf2f(vu.z);
        acc.w += ex * bf2f(vu.w);
    }

    float inv = 1.f / (norm + 1e-8f);
    if ((lane & 7) == 0) invNorm[(size_t)node * HEADS + h] = inv;
    acc.x *= inv; acc.y *= inv; acc.z *= inv; acc.w *= inv;
    *(float4*)(out + (size_t)node * DIM + lane * 4) = acc;
}

// ---------------------------------------------------------------------------
// att_scale: attBuf[e][h] *= invNorm[rows[e]][h]   (finishes softmax)
// ---------------------------------------------------------------------------
__global__ __launch_bounds__(256)
void att_scale(float* __restrict__ attBuf, const float* __restrict__ invNorm,
               const int* __restrict__ rows, int E4)
{
    int t = blockIdx.x * 256 + threadIdx.x;
    if (t >= E4) return;
    int e = t >> 2;
    attBuf[t] *= invNorm[(size_t)rows[e] * 4 + (t & 3)];
}

// ---------------------------------------------------------------------------
// kernel_launch
// ws: Qb,Kb,Vb bf16 [N*128]*3 | WtHi,WtLo bf16 [3*128*128]*2 | invNorm f32[N*4]
//     | rowPtr[N+1] | blockSums[128] | cursor[N] | perm[E] | colsCSR[E]
//     | degree[N]
// ---------------------------------------------------------------------------
extern "C" void kernel_launch(void* const* d_in, const int* in_sizes, int n_in,
                              void* d_out, int out_size, void* d_ws, size_t ws_size,
                              hipStream_t stream)
{
    const float* emb  = (const float*)d_in[0];
    const float* qW   = (const float*)d_in[1];
    const float* kW   = (const float*)d_in[2];
    const float* vW   = (const float*)d_in[3];
    const int*   rows = (const int*)d_in[4];
    const int*   cols = (const int*)d_in[5];

    const int N = in_sizes[0] / DIM;
    const int E = in_sizes[4];

    float* dout   = (float*)d_out;
    float* outMat = dout;                        // [N,128]
    float* attBuf = dout + (size_t)N * DIM;      // [E,4]

    ushort* Qb   = (ushort*)d_ws;
    ushort* Kb   = Qb + (size_t)N * DIM;
    ushort* Vb   = Kb + (size_t)N * DIM;
    ushort* WtHi = Vb + (size_t)N * DIM;
    ushort* WtLo = WtHi + 3 * DIM * DIM;
    float* invNorm = (float*)(WtLo + 3 * DIM * DIM);
    int* rowPtr    = (int*)(invNorm + (size_t)N * HEADS);
    int* blockSums = rowPtr + (N + 1);
    int* cursor    = blockSums + 128;
    int* perm      = cursor + N;
    int* colsCSR   = perm + E;
    int* degree    = colsCSR + E;

    hipMemsetAsync(degree, 0, (size_t)N * sizeof(int), stream);

    wtrans<<<3 * DIM * DIM / 256, 256, 0, stream>>>(qW, kW, vW, WtHi, WtLo);

    int gblk = (N + 127) / 128;
    qkv_mfma<<<gblk, 512, 0, stream>>>(emb, WtHi, WtLo, Qb, Kb, Vb, N);

    int eblocks = (E + 255) / 256;
    count_degree<<<eblocks, 256, 0, stream>>>(rows, degree, E);

    int nb = (N + 1023) / 1024;
    scanA<<<nb, 256, 0, stream>>>(degree, rowPtr, blockSums, N);
    scanB<<<1, 256, 0, stream>>>(blockSums, nb);
    scanC<<<nb, 256, 0, stream>>>(rowPtr, blockSums, cursor, N, E);

    fill_perm<<<eblocks, 256, 0, stream>>>(rows, cols, cursor, perm, colsCSR, E);

    int gblocks = (N * 32 + 255) / 256;
    csr_fused<<<gblocks, 256, 0, stream>>>(Qb, Kb, Vb, rowPtr, perm, colsCSR,
                                           attBuf, invNorm, outMat, N);

    int sblocks = (E * HEADS + 255) / 256;
    att_scale<<<sblocks, 256, 0, stream>>>(attBuf, invNorm, rows, E * HEADS);
}

// Round 5
// 188.595 us; speedup vs baseline: 1.2731x; 1.2731x over previous
//
#include <hip/hip_runtime.h>
#include <cstdint>
#include <cstddef>

#define DIM 128
#define HEADS 4

typedef __attribute__((ext_vector_type(8))) short bf16x8;
typedef __attribute__((ext_vector_type(4))) float f32x4;

__device__ __forceinline__ ushort f2bf(float x) {
    union { float f; uint32_t u; } v; v.f = x;
    uint32_t r = v.u + 0x7FFFu + ((v.u >> 16) & 1u);   // RNE
    return (ushort)(r >> 16);
}
__device__ __forceinline__ float bf2f(ushort h) {
    union { uint32_t u; float f; } v; v.u = ((uint32_t)h) << 16; return v.f;
}

// ---------------------------------------------------------------------------
// prep: fused wtrans (blocks 0..191) + count_degree (blocks 192..)
// wtrans: W[k][col] f32 -> Wt[w][col][k] bf16 hi/lo (transposed for B-frags)
// ---------------------------------------------------------------------------
__global__ __launch_bounds__(256)
void prep(const float* __restrict__ qW, const float* __restrict__ kW,
          const float* __restrict__ vW,
          ushort* __restrict__ WtHi, ushort* __restrict__ WtLo,
          const int* __restrict__ rows, int* __restrict__ degree, int E)
{
    int b = blockIdx.x;
    if (b < 192) {
        int t = b * 256 + threadIdx.x;           // 0..49151
        int w = t >> 14;
        int rem = t & 16383;
        int col = rem >> 7;
        int k = rem & 127;
        const float* W = (w == 0) ? qW : (w == 1) ? kW : vW;
        float x = W[k * DIM + col];
        ushort hi = f2bf(x);
        ushort lo = f2bf(x - bf2f(hi));
        WtHi[t] = hi;                            // [w][col][k]
        WtLo[t] = lo;
    } else {
        int e = (b - 192) * 256 + threadIdx.x;
        if (e < E) atomicAdd(&degree[rows[e]], 1);
    }
}

// ---------------------------------------------------------------------------
// qkv_fused: Q,K,V = emb @ {qW,kW,vW} via 3-term hi/lo bf16 MFMA, one dispatch.
// 256 threads = 4 waves (2M x 2N). Block = 64 rows x 64 cols (by = col half).
// K chunked x32: per chunk stage A-chunk (f32->hi/lo) + B-chunk (all 3 W) in
// LDS, rows padded to 40 ushorts (80B, 16B-aligned, 2-way max bank pattern).
// MFMA per-acc term order: k ascending, (hh, lh, hl) per slice -> bit-exact
// vs R2 (absmax unchanged). LDS 40KB -> 4 blocks/CU.
// ---------------------------------------------------------------------------
#define APAD 40   // 32 k + 8 pad (ushorts); row stride 80B

__global__ __launch_bounds__(256)
void qkv_fused(const float* __restrict__ emb,
               const ushort* __restrict__ WtHi, const ushort* __restrict__ WtLo,
               ushort* __restrict__ Qb, ushort* __restrict__ Kb,
               ushort* __restrict__ Vb, int N)
{
    __shared__ ushort Ahi[64 * APAD], Alo[64 * APAD];          // 5120B each
    __shared__ ushort Bhi[3 * 64 * APAD], Blo[3 * 64 * APAD];  // 15360B each

    const int tid = threadIdx.x;
    const int wv = tid >> 6;
    const int ln = tid & 63;
    const int l15 = ln & 15;
    const int l4 = ln >> 4;
    const int wm = wv >> 1;             // wave row group (32 rows)
    const int wn = wv & 1;              // wave col group (32 cols)
    const int m0 = blockIdx.x * 64;
    const int c0 = blockIdx.y * 64;     // col half

    f32x4 acc[3][2][2] = {};            // [wsel][fr][n]

    for (int c = 0; c < 4; c++) {       // k chunk: k = c*32 .. +32
        // ---- stage A chunk: 64 rows x 32 k, f32 -> bf16 hi/lo ----
        {
            int row = tid >> 2;                 // 0..63
            int k8 = (tid & 3) * 8;             // 0,8,16,24
            float4 a0 = make_float4(0.f, 0.f, 0.f, 0.f);
            float4 a1 = a0;
            if (m0 + row < N) {
                const float* src = emb + (size_t)(m0 + row) * DIM + c * 32 + k8;
                a0 = *(const float4*)(src);
                a1 = *(const float4*)(src + 4);
            }
            ushort4 h0, l0, h1, l1;
            h0.x = f2bf(a0.x); l0.x = f2bf(a0.x - bf2f(h0.x));
            h0.y = f2bf(a0.y); l0.y = f2bf(a0.y - bf2f(h0.y));
            h0.z = f2bf(a0.z); l0.z = f2bf(a0.z - bf2f(h0.z));
            h0.w = f2bf(a0.w); l0.w = f2bf(a0.w - bf2f(h0.w));
            h1.x = f2bf(a1.x); l1.x = f2bf(a1.x - bf2f(h1.x));
            h1.y = f2bf(a1.y); l1.y = f2bf(a1.y - bf2f(h1.y));
            h1.z = f2bf(a1.z); l1.z = f2bf(a1.z - bf2f(h1.z));
            h1.w = f2bf(a1.w); l1.w = f2bf(a1.w - bf2f(h1.w));
            int u = row * APAD + k8;
            *(ushort4*)(Ahi + u) = h0; *(ushort4*)(Ahi + u + 4) = h1;
            *(ushort4*)(Alo + u) = l0; *(ushort4*)(Alo + u + 4) = l1;
        }
        // ---- stage B chunk: 3 x 64 cols x 32 k (bf16 pre-split) ----
#pragma unroll
        for (int p = 0; p < 3; p++) {
            int idx = tid + p * 256;            // 0..767, 8 ushorts each
            int flat = idx * 8;                 // 0..6136
            int w = flat >> 11;                 // /2048 (64*32)
            int rem = flat & 2047;
            int col = rem >> 5;
            int kk8 = rem & 31;                 // 0,8,16,24
            size_t goff = (size_t)w * 16384 + (size_t)(c0 + col) * DIM + c * 32 + kk8;
            uint4 hv = *(const uint4*)(WtHi + goff);
            uint4 lv = *(const uint4*)(WtLo + goff);
            int u = (w * 64 + col) * APAD + kk8;
            *(uint4*)(Bhi + u) = hv;
            *(uint4*)(Blo + u) = lv;
        }
        __syncthreads();

        // ---- MFMA: A frag row=wm*32+fr*16+l15, k=l4*8..+8 ----
        bf16x8 ah[2], al[2];
#pragma unroll
        for (int fr = 0; fr < 2; fr++) {
            int u = (wm * 32 + fr * 16 + l15) * APAD + l4 * 8;
            ah[fr] = *(bf16x8*)(Ahi + u);
            al[fr] = *(bf16x8*)(Alo + u);
        }
#pragma unroll
        for (int w = 0; w < 3; w++) {
#pragma unroll
            for (int n = 0; n < 2; n++) {
                int u = (w * 64 + wn * 32 + n * 16 + l15) * APAD + l4 * 8;
                bf16x8 bh = *(bf16x8*)(Bhi + u);
                bf16x8 bl = *(bf16x8*)(Blo + u);
#pragma unroll
                for (int fr = 0; fr < 2; fr++) {
                    acc[w][fr][n] = __builtin_amdgcn_mfma_f32_16x16x32_bf16(ah[fr], bh, acc[w][fr][n], 0, 0, 0);
                    acc[w][fr][n] = __builtin_amdgcn_mfma_f32_16x16x32_bf16(al[fr], bh, acc[w][fr][n], 0, 0, 0);
                    acc[w][fr][n] = __builtin_amdgcn_mfma_f32_16x16x32_bf16(ah[fr], bl, acc[w][fr][n], 0, 0, 0);
                }
            }
        }
        __syncthreads();
    }

    // ---- epilogue: C/D layout col=lane&15, row=(lane>>4)*4+j ----
#pragma unroll
    for (int w = 0; w < 3; w++) {
        ushort* __restrict__ Out = (w == 0) ? Qb : (w == 1) ? Kb : Vb;
#pragma unroll
        for (int fr = 0; fr < 2; fr++) {
            int rbase = m0 + wm * 32 + fr * 16 + l4 * 4;
#pragma unroll
            for (int n = 0; n < 2; n++) {
                int col = c0 + wn * 32 + n * 16 + l15;
#pragma unroll
                for (int j = 0; j < 4; j++) {
                    int r = rbase + j;
                    if (r < N) Out[(size_t)r * DIM + col] = f2bf(acc[w][fr][n][j]);
                }
            }
        }
    }
}

// ---------------------------------------------------------------------------
// CSR build: exclusive scan of degree -> rowPtr, then permutation fill.
// ---------------------------------------------------------------------------
__global__ __launch_bounds__(256)
void scanA(const int* __restrict__ degree, int* __restrict__ rowPtr,
           int* __restrict__ blockSums, int N)
{
    __shared__ int s[256];
    const int tid = threadIdx.x;
    const int base = blockIdx.x * 1024 + tid * 4;
    int d[4];
    int tsum = 0;
#pragma unroll
    for (int i = 0; i < 4; i++) {
        d[i] = (base + i < N) ? degree[base + i] : 0;
        tsum += d[i];
    }
    s[tid] = tsum;
    __syncthreads();
    for (int off = 1; off < 256; off <<= 1) {
        int v = (tid >= off) ? s[tid - off] : 0;
        __syncthreads();
        s[tid] += v;
        __syncthreads();
    }
    if (tid == 255) blockSums[blockIdx.x] = s[255];
    int running = s[tid] - tsum;
#pragma unroll
    for (int i = 0; i < 4; i++) {
        if (base + i < N) rowPtr[base + i] = running;
        running += d[i];
    }
}

__global__ __launch_bounds__(256)
void scanB(int* __restrict__ blockSums, int nb)
{
    __shared__ int s[256];
    const int tid = threadIdx.x;
    int v = (tid < nb) ? blockSums[tid] : 0;
    s[tid] = v;
    __syncthreads();
    for (int off = 1; off < 256; off <<= 1) {
        int u = (tid >= off) ? s[tid - off] : 0;
        __syncthreads();
        s[tid] += u;
        __syncthreads();
    }
    if (tid < nb) blockSums[tid] = s[tid] - v;
}

__global__ __launch_bounds__(256)
void scanC(int* __restrict__ rowPtr, const int* __restrict__ blockSums,
           int* __restrict__ cursor, int N, int E)
{
    const int tid = threadIdx.x;
    const int base = blockIdx.x * 1024 + tid * 4;
    const int off = blockSums[blockIdx.x];
#pragma unroll
    for (int i = 0; i < 4; i++) {
        int idx = base + i;
        if (idx < N) {
            int v = rowPtr[idx] + off;
            rowPtr[idx] = v;
            cursor[idx] = v;
        }
    }
    if (blockIdx.x == 0 && tid == 0) rowPtr[N] = E;
}

__global__ __launch_bounds__(256)
void fill_perm(const int* __restrict__ rows, const int* __restrict__ cols,
               int* __restrict__ cursor, int* __restrict__ perm,
               int* __restrict__ colsCSR, int E)
{
    int e = blockIdx.x * 256 + threadIdx.x;
    if (e >= E) return;
    int pos = atomicAdd(&cursor[rows[e]], 1);
    perm[pos] = e;
    colsCSR[pos] = cols[e];
}

// ---------------------------------------------------------------------------
// csr_fused: per node (32 lanes), unroll-2 pass over its edges:
// logits (8-lane shfl reduce per head) -> exp -> norm + unnormalized ex*V acc.
// Then in-kernel normalize of attBuf (same-wave RAW, drained by vmcnt(0)).
// Accumulation order identical to R2 (bit-exact).
// ---------------------------------------------------------------------------
__global__ __launch_bounds__(256)
void csr_fused(const ushort* __restrict__ Qb, const ushort* __restrict__ Kb,
               const ushort* __restrict__ Vb,
               const int* __restrict__ rowPtr, const int* __restrict__ perm,
               const int* __restrict__ colsCSR,
               float* __restrict__ attBuf, float* __restrict__ out, int N)
{
    int t = blockIdx.x * 256 + threadIdx.x;
    int node = t >> 5;
    int lane = t & 31;
    if (node >= N) return;

    const int start = rowPtr[node];
    const int end   = rowPtr[node + 1];
    const int h = lane >> 3;

    ushort4 qu = *(const ushort4*)(Qb + (size_t)node * DIM + lane * 4);
    float4 q = make_float4(bf2f(qu.x), bf2f(qu.y), bf2f(qu.z), bf2f(qu.w));

    float norm = 0.f;
    float4 acc = make_float4(0.f, 0.f, 0.f, 0.f);

    int p = start;
    for (; p + 2 <= end; p += 2) {
        int c0 = colsCSR[p];
        int c1 = colsCSR[p + 1];
        int e0 = perm[p];
        int e1 = perm[p + 1];
        ushort4 k0 = *(const ushort4*)(Kb + (size_t)c0 * DIM + lane * 4);
        ushort4 v0 = *(const ushort4*)(Vb + (size_t)c0 * DIM + lane * 4);
        ushort4 k1 = *(const ushort4*)(Kb + (size_t)c1 * DIM + lane * 4);
        ushort4 v1 = *(const ushort4*)(Vb + (size_t)c1 * DIM + lane * 4);
        float d0 = bf2f(k0.x) * q.x + bf2f(k0.y) * q.y
                 + bf2f(k0.z) * q.z + bf2f(k0.w) * q.w;
        float d1 = bf2f(k1.x) * q.x + bf2f(k1.y) * q.y
                 + bf2f(k1.z) * q.z + bf2f(k1.w) * q.w;
        d0 += __shfl_xor(d0, 1, 64);
        d1 += __shfl_xor(d1, 1, 64);
        d0 += __shfl_xor(d0, 2, 64);
        d1 += __shfl_xor(d1, 2, 64);
        d0 += __shfl_xor(d0, 4, 64);
        d1 += __shfl_xor(d1, 4, 64);
        d0 = fminf(fmaxf(d0, -10.f), 10.f);
        d1 = fminf(fmaxf(d1, -10.f), 10.f);
        float ex0 = __expf(d0);
        float ex1 = __expf(d1);
        if ((lane & 7) == 0) {
            attBuf[(size_t)e0 * HEADS + h] = ex0;
            attBuf[(size_t)e1 * HEADS + h] = ex1;
        }
        norm += ex0;
        norm += ex1;
        acc.x += ex0 * bf2f(v0.x);
        acc.y += ex0 * bf2f(v0.y);
        acc.z += ex0 * bf2f(v0.z);
        acc.w += ex0 * bf2f(v0.w);
        acc.x += ex1 * bf2f(v1.x);
        acc.y += ex1 * bf2f(v1.y);
        acc.z += ex1 * bf2f(v1.z);
        acc.w += ex1 * bf2f(v1.w);
    }
    if (p < end) {
        int c = colsCSR[p];
        int e = perm[p];
        ushort4 ku = *(const ushort4*)(Kb + (size_t)c * DIM + lane * 4);
        ushort4 vu = *(const ushort4*)(Vb + (size_t)c * DIM + lane * 4);
        float d = bf2f(ku.x) * q.x + bf2f(ku.y) * q.y
                + bf2f(ku.z) * q.z + bf2f(ku.w) * q.w;
        d += __shfl_xor(d, 1, 64);
        d += __shfl_xor(d, 2, 64);
        d += __shfl_xor(d, 4, 64);
        d = fminf(fmaxf(d, -10.f), 10.f);
        float ex = __expf(d);
        if ((lane & 7) == 0) attBuf[(size_t)e * HEADS + h] = ex;
        norm += ex;
        acc.x += ex * bf2f(vu.x);
        acc.y += ex * bf2f(vu.y);
        acc.z += ex * bf2f(vu.z);
        acc.w += ex * bf2f(vu.w);
    }

    float inv = 1.f / (norm + 1e-8f);
    acc.x *= inv; acc.y *= inv; acc.z *= inv; acc.w *= inv;
    *(float4*)(out + (size_t)node * DIM + lane * 4) = acc;

    // ---- normalize attBuf in place (same-wave RAW: drain stores first) ----
    asm volatile("s_waitcnt vmcnt(0)" ::: "memory");
    if ((lane & 7) == 0) {
        for (int pp = start; pp < end; pp++) {
            int e = perm[pp];
            size_t idx = (size_t)e * HEADS + h;
            attBuf[idx] *= inv;
        }
    }
}

// ---------------------------------------------------------------------------
// kernel_launch
// ws: Qb,Kb,Vb bf16 [N*128]*3 | WtHi,WtLo bf16 [3*128*128]*2
//     | rowPtr[N+1] | blockSums[128] | cursor[N] | perm[E] | colsCSR[E]
//     | degree[N]
// ---------------------------------------------------------------------------
extern "C" void kernel_launch(void* const* d_in, const int* in_sizes, int n_in,
                              void* d_out, int out_size, void* d_ws, size_t ws_size,
                              hipStream_t stream)
{
    const float* emb  = (const float*)d_in[0];
    const float* qW   = (const float*)d_in[1];
    const float* kW   = (const float*)d_in[2];
    const float* vW   = (const float*)d_in[3];
    const int*   rows = (const int*)d_in[4];
    const int*   cols = (const int*)d_in[5];

    const int N = in_sizes[0] / DIM;
    const int E = in_sizes[4];

    float* dout   = (float*)d_out;
    float* outMat = dout;                        // [N,128]
    float* attBuf = dout + (size_t)N * DIM;      // [E,4]

    ushort* Qb   = (ushort*)d_ws;
    ushort* Kb   = Qb + (size_t)N * DIM;
    ushort* Vb   = Kb + (size_t)N * DIM;
    ushort* WtHi = Vb + (size_t)N * DIM;
    ushort* WtLo = WtHi + 3 * DIM * DIM;
    int* rowPtr    = (int*)(WtLo + 3 * DIM * DIM);
    int* blockSums = rowPtr + (N + 1);
    int* cursor    = blockSums + 128;
    int* perm      = cursor + N;
    int* colsCSR   = perm + E;
    int* degree    = colsCSR + E;

    hipMemsetAsync(degree, 0, (size_t)N * sizeof(int), stream);

    int eblocks = (E + 255) / 256;
    prep<<<192 + eblocks, 256, 0, stream>>>(qW, kW, vW, WtHi, WtLo,
                                            rows, degree, E);

    dim3 ggrid((N + 63) / 64, 2);
    qkv_fused<<<ggrid, 256, 0, stream>>>(emb, WtHi, WtLo, Qb, Kb, Vb, N);

    int nb = (N + 1023) / 1024;
    scanA<<<nb, 256, 0, stream>>>(degree, rowPtr, blockSums, N);
    scanB<<<1, 256, 0, stream>>>(blockSums, nb);
    scanC<<<nb, 256, 0, stream>>>(rowPtr, blockSums, cursor, N, E);

    fill_perm<<<eblocks, 256, 0, stream>>>(rows, cols, cursor, perm, colsCSR, E);

    int gblocks = (N * 32 + 255) / 256;
    csr_fused<<<gblocks, 256, 0, stream>>>(Qb, Kb, Vb, rowPtr, perm, colsCSR,
                                           attBuf, outMat, N);
}

// Round 6
// 164.129 us; speedup vs baseline: 1.4628x; 1.1491x over previous
//
#include <hip/hip_runtime.h>
#include <cstdint>
#include <cstddef>

#define DIM 128
#define HEADS 4

typedef __attribute__((ext_vector_type(8))) short bf16x8;
typedef __attribute__((ext_vector_type(4))) float f32x4;

__device__ __forceinline__ ushort f2bf(float x) {
    union { float f; uint32_t u; } v; v.f = x;
    uint32_t r = v.u + 0x7FFFu + ((v.u >> 16) & 1u);   // RNE
    return (ushort)(r >> 16);
}
__device__ __forceinline__ float bf2f(ushort h) {
    union { uint32_t u; float f; } v; v.u = ((uint32_t)h) << 16; return v.f;
}

// ---------------------------------------------------------------------------
// prep: fused wtrans (blocks 0..191) + count_degree (blocks 192..)
// wtrans: W[k][col] f32 -> Wt[w][col][k] bf16 hi/lo (transposed for B-frags)
// ---------------------------------------------------------------------------
__global__ __launch_bounds__(256)
void prep(const float* __restrict__ qW, const float* __restrict__ kW,
          const float* __restrict__ vW,
          ushort* __restrict__ WtHi, ushort* __restrict__ WtLo,
          const int* __restrict__ rows, int* __restrict__ degree, int E)
{
    int b = blockIdx.x;
    if (b < 192) {
        int t = b * 256 + threadIdx.x;           // 0..49151
        int w = t >> 14;
        int rem = t & 16383;
        int col = rem >> 7;
        int k = rem & 127;
        const float* W = (w == 0) ? qW : (w == 1) ? kW : vW;
        float x = W[k * DIM + col];
        ushort hi = f2bf(x);
        ushort lo = f2bf(x - bf2f(hi));
        WtHi[t] = hi;                            // [w][col][k]
        WtLo[t] = lo;
    } else {
        int e = (b - 192) * 256 + threadIdx.x;
        if (e < E) atomicAdd(&degree[rows[e]], 1);
    }
}

// ---------------------------------------------------------------------------
// qkv_fused: Q,K,V = emb @ {qW,kW,vW} via 3-term hi/lo bf16 MFMA, one dispatch.
// 256 threads = 4 waves (2M x 2N). Block = 64 rows x 64 cols (by = col half).
// MFMA math identical to R4 (bit-exact). Epilogue: Q -> Qb[r][128];
// K -> KVb[r][0..127], V -> KVb[r][128..255] (interleaved for gather locality).
// ---------------------------------------------------------------------------
#define APAD 40   // 32 k + 8 pad (ushorts); row stride 80B

__global__ __launch_bounds__(256)
void qkv_fused(const float* __restrict__ emb,
               const ushort* __restrict__ WtHi, const ushort* __restrict__ WtLo,
               ushort* __restrict__ Qb, ushort* __restrict__ KVb, int N)
{
    __shared__ ushort Ahi[64 * APAD], Alo[64 * APAD];          // 5120B each
    __shared__ ushort Bhi[3 * 64 * APAD], Blo[3 * 64 * APAD];  // 15360B each

    const int tid = threadIdx.x;
    const int wv = tid >> 6;
    const int ln = tid & 63;
    const int l15 = ln & 15;
    const int l4 = ln >> 4;
    const int wm = wv >> 1;             // wave row group (32 rows)
    const int wn = wv & 1;              // wave col group (32 cols)
    const int m0 = blockIdx.x * 64;
    const int c0 = blockIdx.y * 64;     // col half

    f32x4 acc[3][2][2] = {};            // [wsel][fr][n]

    for (int c = 0; c < 4; c++) {       // k chunk: k = c*32 .. +32
        // ---- stage A chunk: 64 rows x 32 k, f32 -> bf16 hi/lo ----
        {
            int row = tid >> 2;                 // 0..63
            int k8 = (tid & 3) * 8;             // 0,8,16,24
            float4 a0 = make_float4(0.f, 0.f, 0.f, 0.f);
            float4 a1 = a0;
            if (m0 + row < N) {
                const float* src = emb + (size_t)(m0 + row) * DIM + c * 32 + k8;
                a0 = *(const float4*)(src);
                a1 = *(const float4*)(src + 4);
            }
            ushort4 h0, l0, h1, l1;
            h0.x = f2bf(a0.x); l0.x = f2bf(a0.x - bf2f(h0.x));
            h0.y = f2bf(a0.y); l0.y = f2bf(a0.y - bf2f(h0.y));
            h0.z = f2bf(a0.z); l0.z = f2bf(a0.z - bf2f(h0.z));
            h0.w = f2bf(a0.w); l0.w = f2bf(a0.w - bf2f(h0.w));
            h1.x = f2bf(a1.x); l1.x = f2bf(a1.x - bf2f(h1.x));
            h1.y = f2bf(a1.y); l1.y = f2bf(a1.y - bf2f(h1.y));
            h1.z = f2bf(a1.z); l1.z = f2bf(a1.z - bf2f(h1.z));
            h1.w = f2bf(a1.w); l1.w = f2bf(a1.w - bf2f(h1.w));
            int u = row * APAD + k8;
            *(ushort4*)(Ahi + u) = h0; *(ushort4*)(Ahi + u + 4) = h1;
            *(ushort4*)(Alo + u) = l0; *(ushort4*)(Alo + u + 4) = l1;
        }
        // ---- stage B chunk: 3 x 64 cols x 32 k (bf16 pre-split) ----
#pragma unroll
        for (int p = 0; p < 3; p++) {
            int idx = tid + p * 256;            // 0..767, 8 ushorts each
            int flat = idx * 8;                 // 0..6136
            int w = flat >> 11;                 // /2048 (64*32)
            int rem = flat & 2047;
            int col = rem >> 5;
            int kk8 = rem & 31;                 // 0,8,16,24
            size_t goff = (size_t)w * 16384 + (size_t)(c0 + col) * DIM + c * 32 + kk8;
            uint4 hv = *(const uint4*)(WtHi + goff);
            uint4 lv = *(const uint4*)(WtLo + goff);
            int u = (w * 64 + col) * APAD + kk8;
            *(uint4*)(Bhi + u) = hv;
            *(uint4*)(Blo + u) = lv;
        }
        __syncthreads();

        // ---- MFMA: A frag row=wm*32+fr*16+l15, k=l4*8..+8 ----
        bf16x8 ah[2], al[2];
#pragma unroll
        for (int fr = 0; fr < 2; fr++) {
            int u = (wm * 32 + fr * 16 + l15) * APAD + l4 * 8;
            ah[fr] = *(bf16x8*)(Ahi + u);
            al[fr] = *(bf16x8*)(Alo + u);
        }
#pragma unroll
        for (int w = 0; w < 3; w++) {
#pragma unroll
            for (int n = 0; n < 2; n++) {
                int u = (w * 64 + wn * 32 + n * 16 + l15) * APAD + l4 * 8;
                bf16x8 bh = *(bf16x8*)(Bhi + u);
                bf16x8 bl = *(bf16x8*)(Blo + u);
#pragma unroll
                for (int fr = 0; fr < 2; fr++) {
                    acc[w][fr][n] = __builtin_amdgcn_mfma_f32_16x16x32_bf16(ah[fr], bh, acc[w][fr][n], 0, 0, 0);
                    acc[w][fr][n] = __builtin_amdgcn_mfma_f32_16x16x32_bf16(al[fr], bh, acc[w][fr][n], 0, 0, 0);
                    acc[w][fr][n] = __builtin_amdgcn_mfma_f32_16x16x32_bf16(ah[fr], bl, acc[w][fr][n], 0, 0, 0);
                }
            }
        }
        __syncthreads();
    }

    // ---- epilogue: C/D layout col=lane&15, row=(lane>>4)*4+j ----
#pragma unroll
    for (int w = 0; w < 3; w++) {
#pragma unroll
        for (int fr = 0; fr < 2; fr++) {
            int rbase = m0 + wm * 32 + fr * 16 + l4 * 4;
#pragma unroll
            for (int n = 0; n < 2; n++) {
                int col = c0 + wn * 32 + n * 16 + l15;
#pragma unroll
                for (int j = 0; j < 4; j++) {
                    int r = rbase + j;
                    if (r < N) {
                        ushort val = f2bf(acc[w][fr][n][j]);
                        if (w == 0) Qb[(size_t)r * DIM + col] = val;
                        else        KVb[(size_t)r * 256 + (w - 1) * 128 + col] = val;
                    }
                }
            }
        }
    }
}

// ---------------------------------------------------------------------------
// CSR build: exclusive scan of degree -> rowPtr, then permutation fill.
// ---------------------------------------------------------------------------
__global__ __launch_bounds__(256)
void scanA(const int* __restrict__ degree, int* __restrict__ rowPtr,
           int* __restrict__ blockSums, int N)
{
    __shared__ int s[256];
    const int tid = threadIdx.x;
    const int base = blockIdx.x * 1024 + tid * 4;
    int d[4];
    int tsum = 0;
#pragma unroll
    for (int i = 0; i < 4; i++) {
        d[i] = (base + i < N) ? degree[base + i] : 0;
        tsum += d[i];
    }
    s[tid] = tsum;
    __syncthreads();
    for (int off = 1; off < 256; off <<= 1) {
        int v = (tid >= off) ? s[tid - off] : 0;
        __syncthreads();
        s[tid] += v;
        __syncthreads();
    }
    if (tid == 255) blockSums[blockIdx.x] = s[255];
    int running = s[tid] - tsum;
#pragma unroll
    for (int i = 0; i < 4; i++) {
        if (base + i < N) rowPtr[base + i] = running;
        running += d[i];
    }
}

__global__ __launch_bounds__(256)
void scanB(int* __restrict__ blockSums, int nb)
{
    __shared__ int s[256];
    const int tid = threadIdx.x;
    int v = (tid < nb) ? blockSums[tid] : 0;
    s[tid] = v;
    __syncthreads();
    for (int off = 1; off < 256; off <<= 1) {
        int u = (tid >= off) ? s[tid - off] : 0;
        __syncthreads();
        s[tid] += u;
        __syncthreads();
    }
    if (tid < nb) blockSums[tid] = s[tid] - v;
}

__global__ __launch_bounds__(256)
void scanC(int* __restrict__ rowPtr, const int* __restrict__ blockSums,
           int* __restrict__ cursor, int N, int E)
{
    const int tid = threadIdx.x;
    const int base = blockIdx.x * 1024 + tid * 4;
    const int off = blockSums[blockIdx.x];
#pragma unroll
    for (int i = 0; i < 4; i++) {
        int idx = base + i;
        if (idx < N) {
            int v = rowPtr[idx] + off;
            rowPtr[idx] = v;
            cursor[idx] = v;
        }
    }
    if (blockIdx.x == 0 && tid == 0) rowPtr[N] = E;
}

__global__ __launch_bounds__(256)
void fill_perm(const int* __restrict__ rows, const int* __restrict__ cols,
               int* __restrict__ cursor, int* __restrict__ perm,
               int* __restrict__ colsCSR, int E)
{
    int e = blockIdx.x * 256 + threadIdx.x;
    if (e >= E) return;
    int pos = atomicAdd(&cursor[rows[e]], 1);
    perm[pos] = e;
    colsCSR[pos] = cols[e];
}

// ---------------------------------------------------------------------------
// csr_fused: 16 lanes per node (8 dims/lane), 4 nodes per wave -> 2x the
// independent gather streams of the 32-lane version. Head group = 4 lanes,
// dot reduce via shfl_xor 1,2. Unroll-2 edge loop. Writes ex to attBuf,
// invNorm per (node,head); out = acc*inv written once, coalesced.
// ---------------------------------------------------------------------------
__global__ __launch_bounds__(256)
void csr_fused(const ushort* __restrict__ Qb, const ushort* __restrict__ KVb,
               const int* __restrict__ rowPtr, const int* __restrict__ perm,
               const int* __restrict__ colsCSR,
               float* __restrict__ attBuf, float* __restrict__ invNorm,
               float* __restrict__ out, int N)
{
    int t = blockIdx.x * 256 + threadIdx.x;
    int node = t >> 4;
    int lane = t & 15;                  // 16 lanes/node
    if (node >= N) return;

    const int start = rowPtr[node];
    const int end   = rowPtr[node + 1];
    const int h = lane >> 2;            // head (4 lanes each)

    const ushort* qp = Qb + (size_t)node * DIM + lane * 8;
    ushort4 qu0 = *(const ushort4*)(qp);
    ushort4 qu1 = *(const ushort4*)(qp + 4);
    float q[8] = {bf2f(qu0.x), bf2f(qu0.y), bf2f(qu0.z), bf2f(qu0.w),
                  bf2f(qu1.x), bf2f(qu1.y), bf2f(qu1.z), bf2f(qu1.w)};

    float norm = 0.f;
    float acc[8] = {0.f, 0.f, 0.f, 0.f, 0.f, 0.f, 0.f, 0.f};

    int p = start;
    for (; p + 2 <= end; p += 2) {
        int c0 = colsCSR[p];
        int c1 = colsCSR[p + 1];
        int e0 = perm[p];
        int e1 = perm[p + 1];
        const ushort* kv0 = KVb + (size_t)c0 * 256 + lane * 8;
        const ushort* kv1 = KVb + (size_t)c1 * 256 + lane * 8;
        ushort4 k0a = *(const ushort4*)(kv0);
        ushort4 k0b = *(const ushort4*)(kv0 + 4);
        ushort4 v0a = *(const ushort4*)(kv0 + 128);
        ushort4 v0b = *(const ushort4*)(kv0 + 132);
        ushort4 k1a = *(const ushort4*)(kv1);
        ushort4 k1b = *(const ushort4*)(kv1 + 4);
        ushort4 v1a = *(const ushort4*)(kv1 + 128);
        ushort4 v1b = *(const ushort4*)(kv1 + 132);
        float d0 = bf2f(k0a.x) * q[0] + bf2f(k0a.y) * q[1]
                 + bf2f(k0a.z) * q[2] + bf2f(k0a.w) * q[3]
                 + bf2f(k0b.x) * q[4] + bf2f(k0b.y) * q[5]
                 + bf2f(k0b.z) * q[6] + bf2f(k0b.w) * q[7];
        float d1 = bf2f(k1a.x) * q[0] + bf2f(k1a.y) * q[1]
                 + bf2f(k1a.z) * q[2] + bf2f(k1a.w) * q[3]
                 + bf2f(k1b.x) * q[4] + bf2f(k1b.y) * q[5]
                 + bf2f(k1b.z) * q[6] + bf2f(k1b.w) * q[7];
        d0 += __shfl_xor(d0, 1, 64);
        d1 += __shfl_xor(d1, 1, 64);
        d0 += __shfl_xor(d0, 2, 64);
        d1 += __shfl_xor(d1, 2, 64);
        d0 = fminf(fmaxf(d0, -10.f), 10.f);
        d1 = fminf(fmaxf(d1, -10.f), 10.f);
        float ex0 = __expf(d0);
        float ex1 = __expf(d1);
        if ((lane & 3) == 0) {
            attBuf[(size_t)e0 * HEADS + h] = ex0;
            attBuf[(size_t)e1 * HEADS + h] = ex1;
        }
        norm += ex0;
        norm += ex1;
        acc[0] += ex0 * bf2f(v0a.x);
        acc[1] += ex0 * bf2f(v0a.y);
        acc[2] += ex0 * bf2f(v0a.z);
        acc[3] += ex0 * bf2f(v0a.w);
        acc[4] += ex0 * bf2f(v0b.x);
        acc[5] += ex0 * bf2f(v0b.y);
        acc[6] += ex0 * bf2f(v0b.z);
        acc[7] += ex0 * bf2f(v0b.w);
        acc[0] += ex1 * bf2f(v1a.x);
        acc[1] += ex1 * bf2f(v1a.y);
        acc[2] += ex1 * bf2f(v1a.z);
        acc[3] += ex1 * bf2f(v1a.w);
        acc[4] += ex1 * bf2f(v1b.x);
        acc[5] += ex1 * bf2f(v1b.y);
        acc[6] += ex1 * bf2f(v1b.z);
        acc[7] += ex1 * bf2f(v1b.w);
    }
    if (p < end) {
        int c = colsCSR[p];
        int e = perm[p];
        const ushort* kv = KVb + (size_t)c * 256 + lane * 8;
        ushort4 ka = *(const ushort4*)(kv);
        ushort4 kb = *(const ushort4*)(kv + 4);
        ushort4 va = *(const ushort4*)(kv + 128);
        ushort4 vb = *(const ushort4*)(kv + 132);
        float d = bf2f(ka.x) * q[0] + bf2f(ka.y) * q[1]
                + bf2f(ka.z) * q[2] + bf2f(ka.w) * q[3]
                + bf2f(kb.x) * q[4] + bf2f(kb.y) * q[5]
                + bf2f(kb.z) * q[6] + bf2f(kb.w) * q[7];
        d += __shfl_xor(d, 1, 64);
        d += __shfl_xor(d, 2, 64);
        d = fminf(fmaxf(d, -10.f), 10.f);
        float ex = __expf(d);
        if ((lane & 3) == 0) attBuf[(size_t)e * HEADS + h] = ex;
        norm += ex;
        acc[0] += ex * bf2f(va.x);
        acc[1] += ex * bf2f(va.y);
        acc[2] += ex * bf2f(va.z);
        acc[3] += ex * bf2f(va.w);
        acc[4] += ex * bf2f(vb.x);
        acc[5] += ex * bf2f(vb.y);
        acc[6] += ex * bf2f(vb.z);
        acc[7] += ex * bf2f(vb.w);
    }

    float inv = 1.f / (norm + 1e-8f);
    if ((lane & 3) == 0) invNorm[(size_t)node * HEADS + h] = inv;
    float* op = out + (size_t)node * DIM + lane * 8;
    *(float4*)(op)     = make_float4(acc[0] * inv, acc[1] * inv,
                                     acc[2] * inv, acc[3] * inv);
    *(float4*)(op + 4) = make_float4(acc[4] * inv, acc[5] * inv,
                                     acc[6] * inv, acc[7] * inv);
}

// ---------------------------------------------------------------------------
// att_scale: attBuf[e][h] *= invNorm[rows[e]][h]   (finishes softmax)
// ---------------------------------------------------------------------------
__global__ __launch_bounds__(256)
void att_scale(float* __restrict__ attBuf, const float* __restrict__ invNorm,
               const int* __restrict__ rows, int E4)
{
    int t = blockIdx.x * 256 + threadIdx.x;
    if (t >= E4) return;
    int e = t >> 2;
    attBuf[t] *= invNorm[(size_t)rows[e] * 4 + (t & 3)];
}

// ---------------------------------------------------------------------------
// kernel_launch
// ws: Qb bf16 [N*128] | KVb bf16 [N*256] | WtHi,WtLo bf16 [3*128*128]*2
//     | invNorm f32 [N*4] | rowPtr[N+1] | blockSums[128] | cursor[N]
//     | perm[E] | colsCSR[E] | degree[N]
// ---------------------------------------------------------------------------
extern "C" void kernel_launch(void* const* d_in, const int* in_sizes, int n_in,
                              void* d_out, int out_size, void* d_ws, size_t ws_size,
                              hipStream_t stream)
{
    const float* emb  = (const float*)d_in[0];
    const float* qW   = (const float*)d_in[1];
    const float* kW   = (const float*)d_in[2];
    const float* vW   = (const float*)d_in[3];
    const int*   rows = (const int*)d_in[4];
    const int*   cols = (const int*)d_in[5];

    const int N = in_sizes[0] / DIM;
    const int E = in_sizes[4];

    float* dout   = (float*)d_out;
    float* outMat = dout;                        // [N,128]
    float* attBuf = dout + (size_t)N * DIM;      // [E,4]

    ushort* Qb   = (ushort*)d_ws;
    ushort* KVb  = Qb + (size_t)N * DIM;
    ushort* WtHi = KVb + (size_t)N * 256;
    ushort* WtLo = WtHi + 3 * DIM * DIM;
    float* invNorm = (float*)(WtLo + 3 * DIM * DIM);
    int* rowPtr    = (int*)(invNorm + (size_t)N * HEADS);
    int* blockSums = rowPtr + (N + 1);
    int* cursor    = blockSums + 128;
    int* perm      = cursor + N;
    int* colsCSR   = perm + E;
    int* degree    = colsCSR + E;

    hipMemsetAsync(degree, 0, (size_t)N * sizeof(int), stream);

    int eblocks = (E + 255) / 256;
    prep<<<192 + eblocks, 256, 0, stream>>>(qW, kW, vW, WtHi, WtLo,
                                            rows, degree, E);

    dim3 ggrid((N + 63) / 64, 2);
    qkv_fused<<<ggrid, 256, 0, stream>>>(emb, WtHi, WtLo, Qb, KVb, N);

    int nb = (N + 1023) / 1024;
    scanA<<<nb, 256, 0, stream>>>(degree, rowPtr, blockSums, N);
    scanB<<<1, 256, 0, stream>>>(blockSums, nb);
    scanC<<<nb, 256, 0, stream>>>(rowPtr, blockSums, cursor, N, E);

    fill_perm<<<eblocks, 256, 0, stream>>>(rows, cols, cursor, perm, colsCSR, E);

    int gblocks = (N * 16 + 255) / 256;
    csr_fused<<<gblocks, 256, 0, stream>>>(Qb, KVb, rowPtr, perm, colsCSR,
                                           attBuf, invNorm, outMat, N);

    int sblocks = (E * HEADS + 255) / 256;
    att_scale<<<sblocks, 256, 0, stream>>>(attBuf, invNorm, rows, E * HEADS);
}